// Round 1
// baseline (1071.610 us; speedup 1.0000x reference)
//
#include <hip/hip_runtime.h>

// ---- problem dims ----
#define SQ   2048
#define DM   768
#define NHD  12
#define DHD  64
#define FF   1536
#define NE   8
#define NL   2
#define NV   32000

typedef __attribute__((ext_vector_type(8))) short bf16x8;
typedef __attribute__((ext_vector_type(4))) float f32x4;

__device__ __forceinline__ unsigned short f2bf(float f) {
  unsigned u = __float_as_uint(f);
  return (unsigned short)((u + 0x7fffu + ((u >> 16) & 1u)) >> 16);
}
__device__ __forceinline__ float bf2f(unsigned short h) {
  return __uint_as_float(((unsigned)h) << 16);
}

// ---------------- embedding: x = emb[tok]*sqrt(D) ----------------
__global__ __launch_bounds__(256) void embed_k(const int* __restrict__ tok,
    const float* __restrict__ emb, float* __restrict__ x,
    unsigned short* __restrict__ xbf) {
  int idx = blockIdx.x * 256 + threadIdx.x;   // < 2048*768
  int s = idx / DM, d = idx % DM;
  float v = emb[(size_t)tok[s] * DM + d] * 27.712812921102035f;
  x[idx] = v;
  xbf[idx] = f2bf(v);
}

// ---------------- generic bf16-MFMA GEMM ----------------
// C[z][m][n] = scale * sum_k A[z][row(m)][k] * B[z][n][k] (+ bias[n])
// A always bf16 (ushort). B is bf16 or fp32 (converted during staging).
// GATHER: A row index taken from glist (per-z token lists, M = cnt[z]).
template<bool BF16B, bool GATHER, bool BIAS, bool OBF16>
__global__ __launch_bounds__(256) void gemm_k(
    const unsigned short* __restrict__ A, long long lda, long long a_z,
    const void* __restrict__ Bp, long long ldb, long long b_z,
    const float* __restrict__ bias,
    void* __restrict__ C, long long ldc, long long c_z,
    int M, int N, int Kd, float scale,
    const int* __restrict__ glist, long long gl_z,
    const int* __restrict__ cnt)
{
  int z = blockIdx.z;
  int Mz = cnt ? cnt[z] : M;
  int m0 = blockIdx.y * 128;
  int n0 = blockIdx.x * 128;
  if (m0 >= Mz) return;
  const unsigned short* Ab = A + (size_t)z * a_z;
  const int* gl = nullptr;
  if constexpr (GATHER) gl = glist + (size_t)z * gl_z;

  __shared__ unsigned short As[128][72];  // 64 + 8 pad -> stride 144B (2-way free)
  __shared__ unsigned short Bs[128][72];

  int t = threadIdx.x;
  int w = t >> 6, lane = t & 63;
  int wm = (w >> 1) * 64, wn = (w & 1) * 64;
  int fr = lane & 15, ks = (lane >> 4) * 8;

  f32x4 acc[4][4] = {};

  for (int k0 = 0; k0 < Kd; k0 += 64) {
    // stage A tile (128x64 bf16): 16B per chunk, 4 chunks/thread
    #pragma unroll
    for (int i = 0; i < 4; ++i) {
      int c = t + i * 256;
      int r = c >> 3, sl = c & 7;
      int gr = m0 + r; if (gr >= Mz) gr = Mz - 1;
      int arow; if constexpr (GATHER) arow = gl[gr]; else arow = gr;
      *(int4*)&As[r][sl * 8] =
          *(const int4*)(Ab + (size_t)arow * lda + k0 + sl * 8);
    }
    // stage B tile
    if constexpr (BF16B) {
      const unsigned short* Bb = (const unsigned short*)Bp + (size_t)z * b_z;
      #pragma unroll
      for (int i = 0; i < 4; ++i) {
        int c = t + i * 256;
        int r = c >> 3, sl = c & 7;
        int br = n0 + r; if (br >= N) br = N - 1;
        *(int4*)&Bs[r][sl * 8] =
            *(const int4*)(Bb + (size_t)br * ldb + k0 + sl * 8);
      }
    } else {
      const float* Bb = (const float*)Bp + (size_t)z * b_z;
      #pragma unroll
      for (int i = 0; i < 4; ++i) {
        int c = t + i * 256;
        int r = c >> 3, sl = c & 7;
        int br = n0 + r; if (br >= N) br = N - 1;
        const float* q = Bb + (size_t)br * ldb + k0 + sl * 8;
        float4 f0 = *(const float4*)q;
        float4 f1 = *(const float4*)(q + 4);
        int4 pk = make_int4(
            (int)((unsigned)f2bf(f0.x) | ((unsigned)f2bf(f0.y) << 16)),
            (int)((unsigned)f2bf(f0.z) | ((unsigned)f2bf(f0.w) << 16)),
            (int)((unsigned)f2bf(f1.x) | ((unsigned)f2bf(f1.y) << 16)),
            (int)((unsigned)f2bf(f1.z) | ((unsigned)f2bf(f1.w) << 16)));
        *(int4*)&Bs[r][sl * 8] = pk;
      }
    }
    __syncthreads();
    #pragma unroll
    for (int kb = 0; kb < 2; ++kb) {
      bf16x8 af[4], bv[4];
      #pragma unroll
      for (int m = 0; m < 4; ++m)
        af[m] = *(const bf16x8*)&As[wm + m * 16 + fr][kb * 32 + ks];
      #pragma unroll
      for (int n = 0; n < 4; ++n)
        bv[n] = *(const bf16x8*)&Bs[wn + n * 16 + fr][kb * 32 + ks];
      #pragma unroll
      for (int m = 0; m < 4; ++m)
        #pragma unroll
        for (int n = 0; n < 4; ++n)
          acc[m][n] = __builtin_amdgcn_mfma_f32_16x16x32_bf16(
              af[m], bv[n], acc[m][n], 0, 0, 0);
    }
    __syncthreads();
  }

  // epilogue: C/D layout col=lane&15, row=(lane>>4)*4+reg
  int rb = (lane >> 4) * 4;
  #pragma unroll
  for (int m = 0; m < 4; ++m) {
    #pragma unroll
    for (int n = 0; n < 4; ++n) {
      int col = n0 + wn + n * 16 + fr;
      if (col >= N) continue;
      #pragma unroll
      for (int r = 0; r < 4; ++r) {
        int row = m0 + wm + m * 16 + rb + r;
        if (row >= Mz) continue;
        float v = acc[m][n][r] * scale;
        if constexpr (BIAS) v += bias[col];
        size_t off = (size_t)z * c_z + (size_t)row * ldc + col;
        if constexpr (OBF16) ((unsigned short*)C)[off] = f2bf(v);
        else                 ((float*)C)[off] = v;
      }
    }
  }
}

// ---------------- V transpose: vt[h][d][k] = qkv[k][2D + h*64 + d] ----------------
__global__ __launch_bounds__(256) void transpose_v_k(
    const unsigned short* __restrict__ qkv, unsigned short* __restrict__ vt) {
  int kt = blockIdx.x;   // 0..31
  int h  = blockIdx.y;   // 0..11
  __shared__ unsigned short tile[64][72];
  int t = threadIdx.x;
  int r = t >> 2;             // 0..63
  int c0 = (t & 3) * 16;      // 0,16,32,48
  const unsigned short* src =
      qkv + (size_t)(kt * 64 + r) * (3 * DM) + 2 * DM + h * DHD + c0;
  *(int4*)&tile[r][c0]     = *(const int4*)(src);
  *(int4*)&tile[r][c0 + 8] = *(const int4*)(src + 8);
  __syncthreads();
  unsigned u[8];
  #pragma unroll
  for (int j = 0; j < 8; ++j)
    u[j] = (unsigned)tile[c0 + 2 * j][r] | ((unsigned)tile[c0 + 2 * j + 1][r] << 16);
  unsigned short* dst = vt + (size_t)(h * DHD + r) * SQ + kt * 64 + c0;
  *(int4*)dst       = make_int4((int)u[0], (int)u[1], (int)u[2], (int)u[3]);
  *(int4*)(dst + 8) = make_int4((int)u[4], (int)u[5], (int)u[6], (int)u[7]);
}

// ---------------- softmax over one score row (2048, bf16, in-place) ----------------
__global__ __launch_bounds__(256) void softmax_k(unsigned short* __restrict__ sc) {
  unsigned short* p = sc + (size_t)blockIdx.x * SQ;
  int t = threadIdx.x;
  int4 raw = ((int4*)p)[t];
  unsigned short* h = (unsigned short*)&raw;
  float f[8];
  float mx = -1e30f;
  #pragma unroll
  for (int j = 0; j < 8; ++j) { f[j] = bf2f(h[j]); mx = fmaxf(mx, f[j]); }
  #pragma unroll
  for (int o = 32; o; o >>= 1) mx = fmaxf(mx, __shfl_xor(mx, o));
  __shared__ float rm[4], rs[4];
  int w = t >> 6;
  if ((t & 63) == 0) rm[w] = mx;
  __syncthreads();
  mx = fmaxf(fmaxf(rm[0], rm[1]), fmaxf(rm[2], rm[3]));
  float s = 0.f;
  #pragma unroll
  for (int j = 0; j < 8; ++j) { f[j] = expf(f[j] - mx); s += f[j]; }
  #pragma unroll
  for (int o = 32; o; o >>= 1) s += __shfl_xor(s, o);
  if ((t & 63) == 0) rs[w] = s;
  __syncthreads();
  s = rs[0] + rs[1] + rs[2] + rs[3];
  float inv = 1.f / s;
  #pragma unroll
  for (int j = 0; j < 8; ++j) h[j] = f2bf(f[j] * inv);
  ((int4*)p)[t] = raw;
}

// ---------------- x = LN(x + add) ----------------
__global__ __launch_bounds__(256) void add_ln_k(const float* __restrict__ xin,
    const float* __restrict__ add, const float* __restrict__ w,
    const float* __restrict__ b, float* __restrict__ xout,
    unsigned short* __restrict__ xbf) {
  int row = blockIdx.x, t = threadIdx.x;
  const float* xi = xin + (size_t)row * DM;
  const float* ai = add + (size_t)row * DM;
  float v[3]; float s = 0.f, sq = 0.f;
  #pragma unroll
  for (int i = 0; i < 3; ++i) {
    int idx = t + i * 256;
    v[i] = xi[idx] + ai[idx];
    s += v[i]; sq += v[i] * v[i];
  }
  #pragma unroll
  for (int o = 32; o; o >>= 1) { s += __shfl_xor(s, o); sq += __shfl_xor(sq, o); }
  __shared__ float rsm[4], rqm[4];
  int wv = t >> 6;
  if ((t & 63) == 0) { rsm[wv] = s; rqm[wv] = sq; }
  __syncthreads();
  s = rsm[0] + rsm[1] + rsm[2] + rsm[3];
  sq = rqm[0] + rqm[1] + rqm[2] + rqm[3];
  float mean = s * (1.f / 768.f);
  float var = sq * (1.f / 768.f) - mean * mean;
  float inv = rsqrtf(var + 1e-5f);
  float* xo = xout + (size_t)row * DM;
  unsigned short* xb = xbf + (size_t)row * DM;
  #pragma unroll
  for (int i = 0; i < 3; ++i) {
    int idx = t + i * 256;
    float y = (v[i] - mean) * inv * w[idx] + b[idx];
    xo[idx] = y; xb[idx] = f2bf(y);
  }
}

// ---------------- gate: 8 dots, top-2, softmax, expert bucket lists ----------------
__global__ void gate_topk_k(const float* __restrict__ x, const float* __restrict__ gw,
    float* __restrict__ tw, int* __restrict__ ti, int* __restrict__ cnt,
    int* __restrict__ lists, int* __restrict__ slot) {
  int sIdx = blockIdx.x, lane = threadIdx.x;  // 64 threads
  const float* xr = x + (size_t)sIdx * DM;
  float acc[NE] = {};
  for (int d = lane; d < DM; d += 64) {
    float xv = xr[d];
    #pragma unroll
    for (int e = 0; e < NE; ++e) acc[e] += xv * gw[e * DM + d];
  }
  #pragma unroll
  for (int e = 0; e < NE; ++e) {
    #pragma unroll
    for (int o = 32; o; o >>= 1) acc[e] += __shfl_down(acc[e], o);
  }
  if (lane == 0) {
    float v0 = -1e30f, v1 = -1e30f; int i0 = 0, i1 = 0;
    #pragma unroll
    for (int e = 0; e < NE; ++e) {
      float v = acc[e];
      if (v > v0) { v1 = v0; i1 = i0; v0 = v; i0 = e; }
      else if (v > v1) { v1 = v; i1 = e; }
    }
    float e1 = expf(v1 - v0);
    float inv = 1.f / (1.f + e1);
    tw[sIdx * 2] = inv; tw[sIdx * 2 + 1] = e1 * inv;
    ti[sIdx * 2] = i0;  ti[sIdx * 2 + 1] = i1;
    int p0 = atomicAdd(&cnt[i0], 1); lists[i0 * SQ + p0] = sIdx; slot[sIdx * 2] = p0;
    int p1 = atomicAdd(&cnt[i1], 1); lists[i1 * SQ + p1] = sIdx; slot[sIdx * 2 + 1] = p1;
  }
}

__global__ void zero_k(int* __restrict__ c) {
  if (threadIdx.x < NE) c[threadIdx.x] = 0;
}

// ---------------- hh = silu(hg) * hu (in-place into hg) ----------------
__global__ __launch_bounds__(256) void silu_mul_k(unsigned short* __restrict__ hg,
    const unsigned short* __restrict__ hu, const int* __restrict__ cnt) {
  int e = blockIdx.y, sl = blockIdx.x;
  if (sl >= cnt[e]) return;
  size_t base = ((size_t)e * SQ + sl) * FF;
  int t = threadIdx.x;
  #pragma unroll
  for (int i = 0; i < FF / 256; ++i) {
    size_t idx = base + t + i * 256;
    float g = bf2f(hg[idx]);
    float u = bf2f(hu[idx]);
    float sv = g / (1.f + expf(-g));
    hg[idx] = f2bf(sv * u);
  }
}

// ---------------- moe combine + LN ----------------
__global__ __launch_bounds__(256) void combine_ln_k(const float* __restrict__ xin,
    const float* __restrict__ ye, const float* __restrict__ tw,
    const int* __restrict__ ti, const int* __restrict__ slot,
    const float* __restrict__ w, const float* __restrict__ b,
    float* __restrict__ xout, unsigned short* __restrict__ xbf) {
  int row = blockIdx.x, t = threadIdx.x;
  int e0 = ti[row * 2], e1 = ti[row * 2 + 1];
  int p0 = slot[row * 2], p1 = slot[row * 2 + 1];
  float w0 = tw[row * 2], w1 = tw[row * 2 + 1];
  const float* y0 = ye + ((size_t)e0 * SQ + p0) * DM;
  const float* y1 = ye + ((size_t)e1 * SQ + p1) * DM;
  const float* xi = xin + (size_t)row * DM;
  float v[3]; float s = 0.f, sq = 0.f;
  #pragma unroll
  for (int i = 0; i < 3; ++i) {
    int idx = t + i * 256;
    v[i] = xi[idx] + w0 * y0[idx] + w1 * y1[idx];
    s += v[i]; sq += v[i] * v[i];
  }
  #pragma unroll
  for (int o = 32; o; o >>= 1) { s += __shfl_xor(s, o); sq += __shfl_xor(sq, o); }
  __shared__ float rsm[4], rqm[4];
  int wv = t >> 6;
  if ((t & 63) == 0) { rsm[wv] = s; rqm[wv] = sq; }
  __syncthreads();
  s = rsm[0] + rsm[1] + rsm[2] + rsm[3];
  sq = rqm[0] + rqm[1] + rqm[2] + rqm[3];
  float mean = s * (1.f / 768.f);
  float var = sq * (1.f / 768.f) - mean * mean;
  float inv = rsqrtf(var + 1e-5f);
  float* xo = xout + (size_t)row * DM;
  unsigned short* xb = xbf + (size_t)row * DM;
  #pragma unroll
  for (int i = 0; i < 3; ++i) {
    int idx = t + i * 256;
    float y = (v[i] - mean) * inv * w[idx] + b[idx];
    xo[idx] = y; xb[idx] = f2bf(y);
  }
}

// ---------------- final RMSNorm -> bf16 ----------------
__global__ __launch_bounds__(256) void rms_k(const float* __restrict__ x,
    const float* __restrict__ rw, unsigned short* __restrict__ xbf) {
  int row = blockIdx.x, t = threadIdx.x;
  const float* xi = x + (size_t)row * DM;
  float v[3]; float sq = 0.f;
  #pragma unroll
  for (int i = 0; i < 3; ++i) {
    int idx = t + i * 256;
    v[i] = xi[idx];
    sq += v[i] * v[i];
  }
  #pragma unroll
  for (int o = 32; o; o >>= 1) sq += __shfl_xor(sq, o);
  __shared__ float rqm[4];
  int wv = t >> 6;
  if ((t & 63) == 0) rqm[wv] = sq;
  __syncthreads();
  sq = rqm[0] + rqm[1] + rqm[2] + rqm[3];
  float inv = rsqrtf(sq * (1.f / 768.f) + 1.1920929e-07f);
  unsigned short* xb = xbf + (size_t)row * DM;
  #pragma unroll
  for (int i = 0; i < 3; ++i) {
    int idx = t + i * 256;
    xb[idx] = f2bf(v[i] * inv * rw[idx]);
  }
}

// ================= host =================
extern "C" void kernel_launch(void* const* d_in, const int* in_sizes, int n_in,
                              void* d_out, int out_size, void* d_ws, size_t ws_size,
                              hipStream_t stream) {
  (void)in_sizes; (void)n_in; (void)out_size; (void)ws_size;
  const int*   tokens = (const int*)d_in[0];
  const float* emb    = (const float*)d_in[1];
  const float* qkv_w  = (const float*)d_in[2];
  const float* qkv_b  = (const float*)d_in[3];
  const float* out_w  = (const float*)d_in[4];
  const float* out_b  = (const float*)d_in[5];
  const float* ln1_w  = (const float*)d_in[6];
  const float* ln1_b  = (const float*)d_in[7];
  const float* ln2_w  = (const float*)d_in[8];
  const float* ln2_b  = (const float*)d_in[9];
  const float* gate_w = (const float*)d_in[10];
  const float* eg_w   = (const float*)d_in[11];
  const float* eu_w   = (const float*)d_in[12];
  const float* ed_w   = (const float*)d_in[13];
  const float* rms_w  = (const float*)d_in[14];
  float* out = (float*)d_out;

  char* wsb = (char*)d_ws;
  float*          x_f    = (float*)(wsb + 0);                   // 6291456 B
  unsigned short* x_bf   = (unsigned short*)(wsb + 6291456);    // 3145728
  unsigned short* qkv_bf = (unsigned short*)(wsb + 9437184);    // 9437184
  unsigned short* vt     = (unsigned short*)(wsb + 18874368);   // 3145728
  unsigned short* o_bf   = (unsigned short*)(wsb + 22020096);   // 3145728
  float*          tmp_f  = (float*)(wsb + 25165824);            // 6291456
  float*          tw     = (float*)(wsb + 31457280);            // 16384
  int*            ti     = (int*)(wsb + 31473664);              // 16384
  int*            cnt    = (int*)(wsb + 31490048);              // 256
  int*            lists  = (int*)(wsb + 31490304);              // 65536
  int*            slot   = (int*)(wsb + 31555840);              // 16384
  // big union region @ 31572224: scores(100663296) | hg(50331648)+hu(50331648), ye after
  unsigned short* scores = (unsigned short*)(wsb + 31572224);
  unsigned short* hg     = (unsigned short*)(wsb + 31572224);
  unsigned short* hu     = (unsigned short*)(wsb + 31572224 + 50331648);
  float*          ye     = (float*)(wsb + 31572224 + 100663296);

  embed_k<<<SQ * DM / 256, 256, 0, stream>>>(tokens, emb, x_f, x_bf);

  for (int l = 0; l < NL; ++l) {
    const float* qw = qkv_w + (size_t)l * 3 * DM * DM;
    const float* qb = qkv_b + (size_t)l * 3 * DM;
    const float* ow = out_w + (size_t)l * DM * DM;
    const float* ob = out_b + (size_t)l * DM;
    const float* gw = gate_w + (size_t)l * NE * DM;
    const float* egw = eg_w + (size_t)l * NE * FF * DM;
    const float* euw = eu_w + (size_t)l * NE * FF * DM;
    const float* edw = ed_w + (size_t)l * NE * DM * FF;

    // qkv = x @ qkv_w^T + b  -> bf16
    gemm_k<false, false, true, true><<<dim3(18, 16, 1), 256, 0, stream>>>(
        x_bf, DM, 0, qw, DM, 0, qb, qkv_bf, 3 * DM, 0,
        SQ, 3 * DM, DM, 1.f, nullptr, 0, nullptr);

    transpose_v_k<<<dim3(SQ / 64, NHD), 256, 0, stream>>>(qkv_bf, vt);

    // scores[h] = (Q_h @ K_h^T) / 8  -> bf16
    gemm_k<true, false, false, true><<<dim3(16, 16, NHD), 256, 0, stream>>>(
        qkv_bf, 3 * DM, DHD, qkv_bf + DM, 3 * DM, DHD, nullptr,
        scores, SQ, (long long)SQ * SQ,
        SQ, SQ, DHD, 0.125f, nullptr, 0, nullptr);

    softmax_k<<<NHD * SQ, 256, 0, stream>>>(scores);

    // o[:, h*64:] = P_h @ V_h  (B = vt, row-major [d][k])
    gemm_k<true, false, false, true><<<dim3(1, 16, NHD), 256, 0, stream>>>(
        scores, SQ, (long long)SQ * SQ, vt, SQ, (long long)DHD * SQ, nullptr,
        o_bf, DM, DHD,
        SQ, DHD, SQ, 1.f, nullptr, 0, nullptr);

    // attn out-proj -> tmp_f (fp32)
    gemm_k<false, false, true, false><<<dim3(6, 16, 1), 256, 0, stream>>>(
        o_bf, DM, 0, ow, DM, 0, ob, tmp_f, DM, 0,
        SQ, DM, DM, 1.f, nullptr, 0, nullptr);

    add_ln_k<<<SQ, 256, 0, stream>>>(x_f, tmp_f, ln1_w + l * DM, ln1_b + l * DM,
                                     x_f, x_bf);

    zero_k<<<1, 64, 0, stream>>>(cnt);
    gate_topk_k<<<SQ, 64, 0, stream>>>(x_f, gw, tw, ti, cnt, lists, slot);

    // expert up/gate GEMMs (gathered rows, M = cnt[e])
    gemm_k<false, true, false, true><<<dim3(12, 16, NE), 256, 0, stream>>>(
        x_bf, DM, 0, egw, DM, (long long)FF * DM, nullptr,
        hg, FF, (long long)SQ * FF,
        SQ, FF, DM, 1.f, lists, SQ, cnt);
    gemm_k<false, true, false, true><<<dim3(12, 16, NE), 256, 0, stream>>>(
        x_bf, DM, 0, euw, DM, (long long)FF * DM, nullptr,
        hu, FF, (long long)SQ * FF,
        SQ, FF, DM, 1.f, lists, SQ, cnt);

    silu_mul_k<<<dim3(SQ, NE), 256, 0, stream>>>(hg, hu, cnt);

    // ye = hh @ ed^T (fp32 out)
    gemm_k<false, false, false, false><<<dim3(6, 16, NE), 256, 0, stream>>>(
        hg, FF, (long long)SQ * FF, edw, FF, (long long)DM * FF, nullptr,
        ye, DM, (long long)SQ * DM,
        SQ, DM, FF, 1.f, nullptr, 0, cnt);

    combine_ln_k<<<SQ, 256, 0, stream>>>(x_f, ye, tw, ti, slot,
                                         ln2_w + l * DM, ln2_b + l * DM,
                                         x_f, x_bf);
  }

  rms_k<<<SQ, 256, 0, stream>>>(x_f, rms_w, x_bf);

  // logits = xn @ emb^T (fp32 out)
  gemm_k<false, false, false, false><<<dim3(NV / 128, 16, 1), 256, 0, stream>>>(
      x_bf, DM, 0, emb, DM, 0, nullptr, out, NV, 0,
      SQ, NV, DM, 1.f, nullptr, 0, nullptr);
}